// Round 1
// baseline (165.517 us; speedup 1.0000x reference)
//
#include <hip/hip_runtime.h>
#include <hip/hip_bf16.h>
#include <stdint.h>

// Problem constants (from reference)
#define BB   32
#define LL   4096
#define CCH  64
#define PLh  64
#define PCh  16
#define NPp  256
#define DOUT 512
#define DIN  2048            // PL * 2*PC
#define MM   (BB * NPp)      // 8192 patch-rows

using bf16 = __hip_bfloat16;
typedef __attribute__((ext_vector_type(8))) short bf16x8;  // 8 bf16 = 4 VGPRs (MFMA A/B frag)
typedef __attribute__((ext_vector_type(4))) float f32x4;   // MFMA C/D frag

// Async global->LDS, 16B per lane. LDS dest is wave-uniform base + lane*16.
__device__ __forceinline__ void async_copy16(void* lds, const void* g) {
    __builtin_amdgcn_global_load_lds(
        (const __attribute__((address_space(1))) void*)g,
        (__attribute__((address_space(3))) void*)lds,
        16, 0, 0);
}

// ---------------------------------------------------------------------------
// fp32 -> bf16 weight conversion (vectorized: float4 in, 4x bf16 out)
// ---------------------------------------------------------------------------
__global__ __launch_bounds__(256) void convert_f32_bf16(
    const float* __restrict__ in, bf16* __restrict__ out, int n)
{
    int i = (blockIdx.x * 256 + threadIdx.x) * 4;
    if (i >= n) return;
    float4 v = *(const float4*)(in + i);
    union { bf16 h[4]; uint2 u; } p;
    p.h[0] = __float2bfloat16(v.x);
    p.h[1] = __float2bfloat16(v.y);
    p.h[2] = __float2bfloat16(v.z);
    p.h[3] = __float2bfloat16(v.w);
    *(uint2*)(out + i) = p.u;
}

// ---------------------------------------------------------------------------
// Gather: feats[m][d], d = l*32 + j ; j<16 -> x[b, sL+l, sC+j], j>=16 -> t(sL+l)
// One block per patch m (8192 blocks). Thread t covers d = t*8 .. t*8+7
// (single l per thread since 8 | 32). 16B bf16 store per thread.
// ---------------------------------------------------------------------------
__global__ __launch_bounds__(256) void gather_feats(
    const float* __restrict__ x, const int* __restrict__ startL,
    const int* __restrict__ startC, bf16* __restrict__ feats)
{
    const int m = blockIdx.x;          // patch-row id, b = m / NP
    const int b = m >> 8;              // NP = 256
    const int t = threadIdx.x;
    const int l = t >> 2;              // 0..63
    const int q = t & 3;               // quarter of the 32-wide d-row
    const int sl = startL[m];

    union { bf16 h[8]; uint4 u; } p;
    if (q < 2) {
        const int sc = startC[m];
        const float* src = x + ((size_t)b * LL + (size_t)(sl + l)) * CCH + sc + q * 8;
#pragma unroll
        for (int i = 0; i < 8; ++i) p.h[i] = __float2bfloat16(src[i]);
    } else {
        const bf16 tb = __float2bfloat16((float)(sl + l) * 0.001f);
#pragma unroll
        for (int i = 0; i < 8; ++i) p.h[i] = tb;
    }
    *(uint4*)(feats + (size_t)m * DIN + t * 8) = p.u;
}

// ---------------------------------------------------------------------------
// C[m][n] = act( sum_k A[m][k] * Bt[n][k] + bias[n] )
// m97 structure: 128x128 tile, BK=32, 256 threads (4 waves), each wave a
// 64x64 sub-tile via 4x4 grid of 16x16x32 bf16 MFMAs. global_load_lds x16.
// ---------------------------------------------------------------------------
template <bool SILU, bool OUT_BF16>
__global__ __launch_bounds__(256) void gemm_bt(
    const bf16* __restrict__ A,   // M x K row-major
    const bf16* __restrict__ Bt,  // N x K row-major (i.e. B transposed)
    const float* __restrict__ bias,
    void* __restrict__ outp,      // M x N row-major (bf16 or fp32)
    const int M, const int N, const int K)
{
    constexpr int BK = 32;
    __shared__ __align__(16) bf16 As[128 * BK];
    __shared__ __align__(16) bf16 Bs[128 * BK];

    const int tid  = threadIdx.x;
    const int lane = tid & 63;
    const int wave = tid >> 6;
    const int row0 = blockIdx.x * 128;
    const int col0 = blockIdx.y * 128;

    // Staging: each wave loads 2x16 rows of A-tile and of B-tile.
    // Lane -> (row = lane/4, koff = (lane%4)*8), 16B per lane, matching the
    // hardware's lane*16 LDS placement for row-major [16][32] bf16 chunks.
    const int  srow  = wave * 32 + (lane >> 2);
    const int  skoff = (lane & 3) * 8;
    const bf16* agp = A  + (size_t)(row0 + srow) * K + skoff;
    const bf16* bgp = Bt + (size_t)(col0 + srow) * K + skoff;
    bf16* as_dst0 = &As[(wave * 32 +  0) * BK];
    bf16* as_dst1 = &As[(wave * 32 + 16) * BK];
    bf16* bs_dst0 = &Bs[(wave * 32 +  0) * BK];
    bf16* bs_dst1 = &Bs[(wave * 32 + 16) * BK];

    // Compute: wave (w>>1, w&1) owns rows [mw, mw+64), cols [nw, nw+64).
    const int mw = (wave >> 1) * 64;
    const int nw = (wave & 1) * 64;
    const int fr = lane & 15;   // A-row / B-col within 16x16 tile
    const int fq = lane >> 4;   // k-quad

    f32x4 acc[4][4] = {};

    for (int k0 = 0; k0 < K; k0 += BK) {
        __syncthreads();                       // prev iter's ds_reads done
        async_copy16(as_dst0, agp + k0);
        async_copy16(as_dst1, agp + (size_t)16 * K + k0);
        async_copy16(bs_dst0, bgp + k0);
        async_copy16(bs_dst1, bgp + (size_t)16 * K + k0);
        __syncthreads();                       // staging complete

        bf16x8 af[4], bfm[4];
#pragma unroll
        for (int i = 0; i < 4; ++i)
            af[i] = *(const bf16x8*)&As[(mw + i * 16 + fr) * BK + fq * 8];
#pragma unroll
        for (int j = 0; j < 4; ++j)
            bfm[j] = *(const bf16x8*)&Bs[(nw + j * 16 + fr) * BK + fq * 8];
#pragma unroll
        for (int i = 0; i < 4; ++i)
#pragma unroll
            for (int j = 0; j < 4; ++j)
                acc[i][j] = __builtin_amdgcn_mfma_f32_16x16x32_bf16(
                    af[i], bfm[j], acc[i][j], 0, 0, 0);
    }

    // Epilogue. C/D mapping (verified m89/m91): col = lane&15, row = (lane>>4)*4 + r
#pragma unroll
    for (int j = 0; j < 4; ++j) {
        const int col = col0 + nw + j * 16 + fr;
        const float bv = bias[col];
#pragma unroll
        for (int i = 0; i < 4; ++i) {
#pragma unroll
            for (int r = 0; r < 4; ++r) {
                const int row = row0 + mw + i * 16 + fq * 4 + r;
                float v = acc[i][j][r] + bv;
                if (SILU) v = v / (1.0f + __expf(-v));
                if (OUT_BF16)
                    ((bf16*)outp)[(size_t)row * N + col] = __float2bfloat16(v);
                else
                    ((float*)outp)[(size_t)row * N + col] = v;
            }
        }
    }
}

// ---------------------------------------------------------------------------
extern "C" void kernel_launch(void* const* d_in, const int* in_sizes, int n_in,
                              void* d_out, int out_size, void* d_ws, size_t ws_size,
                              hipStream_t stream)
{
    const float* x  = (const float*)d_in[0];
    const int*   sL = (const int*)  d_in[1];
    const int*   sC = (const int*)  d_in[2];
    const float* w1 = (const float*)d_in[3];
    const float* b1 = (const float*)d_in[4];
    const float* w2 = (const float*)d_in[5];
    const float* b2 = (const float*)d_in[6];
    float* out = (float*)d_out;

    // Workspace layout (bytes):
    char* ws = (char*)d_ws;
    bf16* featsB = (bf16*)ws;                                   // 8192*2048*2 = 32 MB
    size_t off = (size_t)MM * DIN * 2;
    bf16* w1B = (bf16*)(ws + off);  off += (size_t)DOUT * DIN * 2;   // 2 MB
    bf16* w2B = (bf16*)(ws + off);  off += (size_t)DOUT * DOUT * 2;  // 0.5 MB
    bf16* hB  = (bf16*)(ws + off);                                   // 8192*512*2 = 8 MB

    // 1) weights -> bf16
    convert_f32_bf16<<<(DOUT * DIN / 4 + 255) / 256, 256, 0, stream>>>(w1, w1B, DOUT * DIN);
    convert_f32_bf16<<<(DOUT * DOUT / 4 + 255) / 256, 256, 0, stream>>>(w2, w2B, DOUT * DOUT);

    // 2) gather feats (bf16)
    gather_feats<<<MM, 256, 0, stream>>>(x, sL, sC, featsB);

    // 3) h = silu(feats @ w1^T + b1)   [8192 x 512], bf16
    gemm_bt<true, true><<<dim3(MM / 128, DOUT / 128), 256, 0, stream>>>(
        featsB, w1B, b1, hB, MM, DOUT, DIN);

    // 4) out = h @ w2^T + b2           [8192 x 512], fp32
    gemm_bt<false, false><<<dim3(MM / 128, DOUT / 128), 256, 0, stream>>>(
        hB, w2B, b2, out, MM, DOUT, DOUT);
}

// Round 2
// 133.693 us; speedup vs baseline: 1.2380x; 1.2380x over previous
//
#include <hip/hip_runtime.h>
#include <hip/hip_bf16.h>
#include <stdint.h>

// Problem constants
#define BB   32
#define LL   4096
#define CCH  64
#define PLh  64
#define PCh  16
#define NPp  256
#define DOUT 512
#define DINX 1024            // x-part only: PL * PC (t-part folded analytically)
#define MM   (BB * NPp)      // 8192 patch-rows
#define TT   0.001f          // 1/FS

using bf16 = __hip_bfloat16;
typedef __attribute__((ext_vector_type(8))) short bf16x8;
typedef __attribute__((ext_vector_type(4))) float f32x4;

__device__ __forceinline__ void async_copy16(void* lds, const void* g) {
    __builtin_amdgcn_global_load_lds(
        (const __attribute__((address_space(1))) void*)g,
        (__attribute__((address_space(3))) void*)lds,
        16, 0, 0);
}

// ---------------------------------------------------------------------------
// fp32 -> bf16 (dense, for w2)
// ---------------------------------------------------------------------------
__global__ __launch_bounds__(256) void convert_f32_bf16(
    const float* __restrict__ in, bf16* __restrict__ out, int n)
{
    int i = (blockIdx.x * 256 + threadIdx.x) * 4;
    if (i >= n) return;
    float4 v = *(const float4*)(in + i);
    union { bf16 h[4]; uint2 u; } p;
    p.h[0] = __float2bfloat16(v.x);
    p.h[1] = __float2bfloat16(v.y);
    p.h[2] = __float2bfloat16(v.z);
    p.h[3] = __float2bfloat16(v.w);
    *(uint2*)(out + i) = p.u;
}

// ---------------------------------------------------------------------------
// Extract x-columns of w1 -> bf16: w1x[o][l*16+j] = w1[o][l*32+j], j<16
// ---------------------------------------------------------------------------
__global__ __launch_bounds__(256) void convert_w1x(
    const float* __restrict__ w1, bf16* __restrict__ w1x)
{
    int i = (blockIdx.x * 256 + threadIdx.x) * 4;   // out index, n = 512*1024
    int o = i >> 10, r = i & 1023;
    int l = r >> 4, j = r & 15;
    float4 v = *(const float4*)(w1 + (size_t)o * 2048 + l * 32 + j);
    union { bf16 h[4]; uint2 u; } p;
    p.h[0] = __float2bfloat16(v.x);
    p.h[1] = __float2bfloat16(v.y);
    p.h[2] = __float2bfloat16(v.z);
    p.h[3] = __float2bfloat16(v.w);
    *(uint2*)(w1x + i) = p.u;
}

// ---------------------------------------------------------------------------
// Precompute affine t-terms per output unit o:
//   W1t[o][l] = sum_{j<16} w1[o][l*32+16+j]
//   A1[o] = T * sum_l W1t[o][l]          (coefficient of sL)
//   C1[o] = b1[o] + T * sum_l l*W1t[o][l]
// One wave per o.
// ---------------------------------------------------------------------------
__global__ __launch_bounds__(64) void precompute_affine(
    const float* __restrict__ w1, const float* __restrict__ b1,
    float* __restrict__ A1, float* __restrict__ C1)
{
    const int o = blockIdx.x;
    const int l = threadIdx.x;        // 0..63
    const float* wr = w1 + (size_t)o * 2048 + l * 32 + 16;
    float s0 = 0.f;
#pragma unroll
    for (int j = 0; j < 16; ++j) s0 += wr[j];
    float s1 = (float)l * s0;
#pragma unroll
    for (int off = 32; off > 0; off >>= 1) {
        s0 += __shfl_down(s0, off);
        s1 += __shfl_down(s1, off);
    }
    if (l == 0) {
        A1[o] = TT * s0;
        C1[o] = b1[o] + TT * s1;
    }
}

// ---------------------------------------------------------------------------
// Gather x-part feats (bf16): feats[m][l*16+j] = x[b, sL[m]+l, sC[m]+j]
// Block per patch m; thread t -> l = t>>2, j0 = (t&3)*4 (4 elems).
// ---------------------------------------------------------------------------
__global__ __launch_bounds__(256) void gather_feats(
    const float* __restrict__ x, const int* __restrict__ startL,
    const int* __restrict__ startC, bf16* __restrict__ feats)
{
    const int m = blockIdx.x;
    const int b = m >> 8;
    const int t = threadIdx.x;
    const int l = t >> 2;
    const int j0 = (t & 3) * 4;
    const int sl = startL[m];
    const int sc = startC[m];
    const float* src = x + ((size_t)b * LL + (size_t)(sl + l)) * CCH + sc + j0;
    union { bf16 h[4]; uint2 u; } p;
#pragma unroll
    for (int i = 0; i < 4; ++i) p.h[i] = __float2bfloat16(src[i]);
    *(uint2*)(feats + (size_t)m * DINX + t * 4) = p.u;
}

// ---------------------------------------------------------------------------
// GEMM, 64x64 tile, BK=32, 256 threads (4 waves), wave -> 32x32 via 2x2 MFMAs.
// FUSE1: out = bf16 silu(acc + sL[row]*A1[col] + C1[col])
// else : out = fp32 (acc + bias[col])
// ---------------------------------------------------------------------------
template <bool FUSE1>
__global__ __launch_bounds__(256) void gemm_bt(
    const bf16* __restrict__ A,   // M x K row-major
    const bf16* __restrict__ Bt,  // N x K row-major
    const float* __restrict__ bias,   // FUSE1: A1 ; else: bias
    const float* __restrict__ C1,     // FUSE1 only
    const int*   __restrict__ sL,     // FUSE1 only (flattened, index = row)
    void* __restrict__ outp,
    const int N, const int K)
{
    constexpr int BK = 32;
    __shared__ __align__(16) bf16 As[64 * BK];
    __shared__ __align__(16) bf16 Bs[64 * BK];

    const int tid  = threadIdx.x;
    const int lane = tid & 63;
    const int wave = tid >> 6;
    const int row0 = blockIdx.x * 64;
    const int col0 = blockIdx.y * 64;

    // Staging: each wave copies 16 rows (1KB) of A and of B per K-iter.
    const int  srow  = wave * 16 + (lane >> 2);
    const int  skoff = (lane & 3) * 8;
    const bf16* agp = A  + (size_t)(row0 + srow) * K + skoff;
    const bf16* bgp = Bt + (size_t)(col0 + srow) * K + skoff;
    bf16* as_dst = &As[wave * 16 * BK];
    bf16* bs_dst = &Bs[wave * 16 * BK];

    const int mw = (wave >> 1) * 32;
    const int nw = (wave & 1) * 32;
    const int fr = lane & 15;
    const int fq = lane >> 4;

    f32x4 acc[2][2] = {};

    for (int k0 = 0; k0 < K; k0 += BK) {
        __syncthreads();
        async_copy16(as_dst, agp + k0);
        async_copy16(bs_dst, bgp + k0);
        __syncthreads();

        bf16x8 af[2], bfm[2];
#pragma unroll
        for (int i = 0; i < 2; ++i)
            af[i] = *(const bf16x8*)&As[(mw + i * 16 + fr) * BK + fq * 8];
#pragma unroll
        for (int j = 0; j < 2; ++j)
            bfm[j] = *(const bf16x8*)&Bs[(nw + j * 16 + fr) * BK + fq * 8];
#pragma unroll
        for (int i = 0; i < 2; ++i)
#pragma unroll
            for (int j = 0; j < 2; ++j)
                acc[i][j] = __builtin_amdgcn_mfma_f32_16x16x32_bf16(
                    af[i], bfm[j], acc[i][j], 0, 0, 0);
    }

    // Per-thread output rows (8 of them), preload sL if fusing
    float slr[2][4];
    if (FUSE1) {
#pragma unroll
        for (int i = 0; i < 2; ++i)
#pragma unroll
            for (int r = 0; r < 4; ++r)
                slr[i][r] = (float)sL[row0 + mw + i * 16 + fq * 4 + r];
    }

#pragma unroll
    for (int j = 0; j < 2; ++j) {
        const int col = col0 + nw + j * 16 + fr;
        const float bv = bias[col];                       // A1[col] when FUSE1
        const float cv = FUSE1 ? C1[col] : 0.f;
#pragma unroll
        for (int i = 0; i < 2; ++i) {
#pragma unroll
            for (int r = 0; r < 4; ++r) {
                const int row = row0 + mw + i * 16 + fq * 4 + r;
                float v;
                if (FUSE1) {
                    v = acc[i][j][r] + slr[i][r] * bv + cv;
                    v = v / (1.0f + __expf(-v));
                    ((bf16*)outp)[(size_t)row * N + col] = __float2bfloat16(v);
                } else {
                    v = acc[i][j][r] + bv;
                    ((float*)outp)[(size_t)row * N + col] = v;
                }
            }
        }
    }
}

// ---------------------------------------------------------------------------
extern "C" void kernel_launch(void* const* d_in, const int* in_sizes, int n_in,
                              void* d_out, int out_size, void* d_ws, size_t ws_size,
                              hipStream_t stream)
{
    const float* x  = (const float*)d_in[0];
    const int*   sL = (const int*)  d_in[1];
    const int*   sC = (const int*)  d_in[2];
    const float* w1 = (const float*)d_in[3];
    const float* b1 = (const float*)d_in[4];
    const float* w2 = (const float*)d_in[5];
    const float* b2 = (const float*)d_in[6];
    float* out = (float*)d_out;

    char* ws = (char*)d_ws;
    bf16* featsB = (bf16*)ws;                      // 8192*1024*2 = 16 MB
    size_t off = (size_t)MM * DINX * 2;
    bf16* w1xB = (bf16*)(ws + off); off += (size_t)DOUT * DINX * 2;  // 1 MB
    bf16* w2B  = (bf16*)(ws + off); off += (size_t)DOUT * DOUT * 2;  // 0.5 MB
    bf16* hB   = (bf16*)(ws + off); off += (size_t)MM * DOUT * 2;    // 8 MB
    float* A1  = (float*)(ws + off); off += DOUT * 4;
    float* C1  = (float*)(ws + off);

    // Prep (independent, all tiny)
    convert_w1x<<<(DOUT * DINX / 4 + 255) / 256, 256, 0, stream>>>(w1, w1xB);
    convert_f32_bf16<<<(DOUT * DOUT / 4 + 255) / 256, 256, 0, stream>>>(w2, w2B, DOUT * DOUT);
    precompute_affine<<<DOUT, 64, 0, stream>>>(w1, b1, A1, C1);
    gather_feats<<<MM, 256, 0, stream>>>(x, sL, sC, featsB);

    // GEMM1: h = silu(feats @ w1x^T + sL*A1 + C1)   [8192 x 512] bf16
    gemm_bt<true><<<dim3(MM / 64, DOUT / 64), 256, 0, stream>>>(
        featsB, w1xB, A1, C1, sL, hB, DOUT, DINX);

    // GEMM2: out = h @ w2^T + b2                    [8192 x 512] fp32
    gemm_bt<false><<<dim3(MM / 64, DOUT / 64), 256, 0, stream>>>(
        hB, w2B, b2, nullptr, nullptr, out, DOUT, DOUT);
}